// Round 4
// baseline (113.671 us; speedup 1.0000x reference)
//
#include <hip/hip_runtime.h>
#include <stdint.h>

// BloomFilterer forward:
//   x = 131071*a + 524287*b + 2147483647*c   (int64)
//   repeat rounds(=10): x = hash(x); result &= bit_array[x mod num_bits]
//   out = (int32) !result
//
// Round 4: batched-MLP probing. The hash chain is independent of gathered
// bits, so each wave issues probes in chunks of 5 back-to-back (5 in-flight
// random gathers), consumes them, ballots once per chunk. Serialized latency
// windows per wave: ~7.5 -> ~1.9. Chunk-2 probes are exec-masked to lanes
// still alive (~3%), bounding wasted traffic.

#define HASH_C1 2146121005ull
#define HASH_C2 2221713035ull

__device__ __forceinline__ long long hash_step(long long x) {
    x = x ^ (x >> 16);
    x = (long long)((unsigned long long)x * HASH_C1);
    x = x ^ (x >> 15);
    x = (long long)((unsigned long long)x * HASH_C2);
    x = x ^ (x >> 16);
    return x;
}

// floored mod d (matches jnp.mod), Barrett with M = floor(2^89/d), d in (2^27,2^28)
__device__ __forceinline__ long long mod_d(long long x, long long d,
                                           unsigned long long M) {
    bool neg = x < 0;
    unsigned long long u = neg ? (0ull - (unsigned long long)x)
                               : (unsigned long long)x;
    unsigned long long q  = __umul64hi(u, M) >> 25;
    unsigned long long rr = u - q * (unsigned long long)d;
    if (rr >= (unsigned long long)d) rr -= (unsigned long long)d;
    if (rr >= (unsigned long long)d) rr -= (unsigned long long)d;
    return neg ? (rr ? d - (long long)rr : 0ll) : (long long)rr;
}

__device__ __forceinline__ bool probe(const void* bitsv, int bdt, long long idx) {
    if (bdt == 0)      return ((const uint8_t*)bitsv)[idx] != 0;
    else if (bdt == 1) return ((const uint32_t*)bitsv)[idx] != 0u;
    else               return ((const unsigned long long*)bitsv)[idx] != 0ull;
}

__global__ __launch_bounds__(256) void bloom_mlp(
    const void* __restrict__ nbv,
    const void* __restrict__ bitsv,
    const uint32_t* __restrict__ rounds_p,
    int* __restrict__ out,
    int n_rows,
    long long d,
    unsigned long long M)
{
    __shared__ int s_nb64, s_bdt, s_rounds;

    // ---- per-block dtype detection, wave 0, lane-parallel ----
    if (threadIdx.x < 64) {
        int lane = threadIdx.x;
        const uint32_t* bw = (const uint32_t*)bitsv;
        bool anyf = false, alli = true, oddz = true;
        #pragma unroll
        for (int j = 0; j < 8; ++j) {
            int i = lane * 8 + j;
            uint32_t w = bw[i];
            if (w == 0x3F800000u) anyf = true;
            if (w > 1u) alli = false;
            if ((i & 1) && w != 0u) oddz = false;
        }
        unsigned long long m_anyf = __ballot(anyf);
        unsigned long long m_alli = __ballot(alli);
        unsigned long long m_oddz = __ballot(oddz);
        const uint32_t* nw = (const uint32_t*)nbv;
        bool odd_nz = (lane < 16) ? (nw[2 * lane + 1] != 0u) : false;
        unsigned long long m_nb = __ballot(odd_nz);
        if (lane == 0) {
            int bdt;
            if (m_anyf != 0ull)       bdt = 1;                         // float32
            else if (m_alli == ~0ull) bdt = (m_oddz == ~0ull) ? 3 : 1; // int64:int32
            else                      bdt = 0;                         // uint8
            s_bdt    = bdt;
            s_nb64   = (m_nb == 0ull) ? 1 : 0;
            s_rounds = (int)rounds_p[0];
        }
    }
    __syncthreads();

    const int nb64   = s_nb64;
    const int bdt    = s_bdt;
    const int rounds = s_rounds;

    int row = blockIdx.x * 256 + threadIdx.x;
    if (row >= n_rows) return;

    long long a, b, c;
    {
        long long base = (long long)row * 3;
        if (nb64) {
            const long long* nb = (const long long*)nbv;
            a = nb[base]; b = nb[base + 1]; c = nb[base + 2];
        } else {
            const int* nb = (const int*)nbv;
            a = nb[base]; b = nb[base + 1]; c = nb[base + 2];
        }
    }
    long long x = 131071LL * a + 524287LL * b + 2147483647LL * c;

    bool res = true;

    if (rounds == 10) {
        // ---- chunk 1: 5 probes issued back-to-back, consumed together ----
        {
            bool b0, b1, b2, b3, b4;
            x = hash_step(x); b0 = probe(bitsv, bdt, mod_d(x, d, M));
            x = hash_step(x); b1 = probe(bitsv, bdt, mod_d(x, d, M));
            x = hash_step(x); b2 = probe(bitsv, bdt, mod_d(x, d, M));
            x = hash_step(x); b3 = probe(bitsv, bdt, mod_d(x, d, M));
            x = hash_step(x); b4 = probe(bitsv, bdt, mod_d(x, d, M));
            res = b0 & b1 & b2 & b3 & b4;
        }
        if (__ballot(res) == 0ull) { out[row] = 1; return; }
        // ---- chunk 2: only surviving lanes issue loads (exec-masked) ----
        {
            bool b0 = true, b1 = true, b2 = true, b3 = true, b4 = true;
            long long x2 = hash_step(x);
            long long x3 = hash_step(x2);
            long long x4 = hash_step(x3);
            long long x5 = hash_step(x4);
            long long x6 = hash_step(x5);
            if (res) {
                b0 = probe(bitsv, bdt, mod_d(x2, d, M));
                b1 = probe(bitsv, bdt, mod_d(x3, d, M));
                b2 = probe(bitsv, bdt, mod_d(x4, d, M));
                b3 = probe(bitsv, bdt, mod_d(x5, d, M));
                b4 = probe(bitsv, bdt, mod_d(x6, d, M));
            }
            res = res & b0 & b1 & b2 & b3 & b4;
        }
    } else {
        // generic fallback: serialized early-exit loop
        for (int r = 0; r < rounds; ++r) {
            if (__ballot(res) == 0ull) break;
            if (res) {
                x = hash_step(x);
                res = probe(bitsv, bdt, mod_d(x, d, M));
            }
        }
    }

    out[row] = res ? 0 : 1;
}

extern "C" void kernel_launch(void* const* d_in, const int* in_sizes, int n_in,
                              void* d_out, int out_size, void* d_ws, size_t ws_size,
                              hipStream_t stream)
{
    const void* nb       = d_in[0];
    const void* bits     = d_in[1];
    // d_in[2] = mersenne (1,3) — constants hardcoded
    const uint32_t* rnds = (const uint32_t*)d_in[3];

    int n_rows  = in_sizes[0] / 3;
    long long d = (long long)in_sizes[1];

    unsigned long long M =
        (unsigned long long)(((unsigned __int128)1 << 89) / (unsigned long long)d);

    int blocks = (n_rows + 255) / 256;
    bloom_mlp<<<blocks, 256, 0, stream>>>(nb, bits, rnds, (int*)d_out,
                                          n_rows, d, M);
}

// Round 5
// 61.872 us; speedup vs baseline: 1.8372x; 1.8372x over previous
//
#include <hip/hip_runtime.h>
#include <stdint.h>

// BloomFilterer forward:
//   x = 131071*a + 524287*b + 2147483647*c   (int64)
//   repeat rounds(=10): x = hash(x); result &= bit_array[x mod num_bits]
//   out = (int32) !result
//
// Round 5: multi-chain. 4 rows per thread -> 4 independent gathers in flight
// per wave per round (dead chains gather line 0 = broadcast, free). Early-exit
// per chain (predicated), wave exits when all 256 chains dead. Probe traffic
// identical to the minimal serial version (~2.1M lines); concurrency x4.

#define HASH_C1 2146121005ull
#define HASH_C2 2221713035ull
#define NCHAIN 4

__device__ __forceinline__ long long hash_step(long long x) {
    x = x ^ (x >> 16);
    x = (long long)((unsigned long long)x * HASH_C1);
    x = x ^ (x >> 15);
    x = (long long)((unsigned long long)x * HASH_C2);
    x = x ^ (x >> 16);
    return x;
}

// floored mod d (matches jnp.mod), Barrett with M = floor(2^89/d), d in (2^27,2^28)
__device__ __forceinline__ long long mod_d(long long x, long long d,
                                           unsigned long long M) {
    bool neg = x < 0;
    unsigned long long u = neg ? (0ull - (unsigned long long)x)
                               : (unsigned long long)x;
    unsigned long long q  = __umul64hi(u, M) >> 25;
    unsigned long long rr = u - q * (unsigned long long)d;
    if (rr >= (unsigned long long)d) rr -= (unsigned long long)d;
    if (rr >= (unsigned long long)d) rr -= (unsigned long long)d;
    return neg ? (rr ? d - (long long)rr : 0ll) : (long long)rr;
}

__device__ __forceinline__ bool probe(const void* bitsv, int bdt, long long idx) {
    if (bdt == 0)      return ((const uint8_t*)bitsv)[idx] != 0;
    else if (bdt == 1) return ((const uint32_t*)bitsv)[idx] != 0u;
    else               return ((const unsigned long long*)bitsv)[idx] != 0ull;
}

__global__ __launch_bounds__(256, 4) void bloom_mc(
    const void* __restrict__ nbv,
    const void* __restrict__ bitsv,
    const uint32_t* __restrict__ rounds_p,
    int* __restrict__ out,
    int n_rows,
    long long d,
    unsigned long long M)
{
    __shared__ int s_nb64, s_bdt, s_rounds;

    // ---- per-block dtype detection, wave 0, lane-parallel ----
    if (threadIdx.x < 64) {
        int lane = threadIdx.x;
        const uint32_t* bw = (const uint32_t*)bitsv;
        bool anyf = false, alli = true, oddz = true;
        #pragma unroll
        for (int j = 0; j < 8; ++j) {
            int i = lane * 8 + j;
            uint32_t w = bw[i];
            if (w == 0x3F800000u) anyf = true;
            if (w > 1u) alli = false;
            if ((i & 1) && w != 0u) oddz = false;
        }
        unsigned long long m_anyf = __ballot(anyf);
        unsigned long long m_alli = __ballot(alli);
        unsigned long long m_oddz = __ballot(oddz);
        const uint32_t* nw = (const uint32_t*)nbv;
        bool odd_nz = (lane < 16) ? (nw[2 * lane + 1] != 0u) : false;
        unsigned long long m_nb = __ballot(odd_nz);
        if (lane == 0) {
            int bdt;
            if (m_anyf != 0ull)       bdt = 1;                         // float32
            else if (m_alli == ~0ull) bdt = (m_oddz == ~0ull) ? 3 : 1; // int64:int32
            else                      bdt = 0;                         // uint8
            s_bdt    = bdt;
            s_nb64   = (m_nb == 0ull) ? 1 : 0;
            s_rounds = (int)rounds_p[0];
        }
    }
    __syncthreads();

    const int nb64   = s_nb64;
    const int bdt    = s_bdt;
    const int rounds = s_rounds;

    const long long base_row = (long long)blockIdx.x * (256 * NCHAIN) + threadIdx.x;

    long long x[NCHAIN];
    long long rowid[NCHAIN];
    unsigned alive = 0;

    #pragma unroll
    for (int c = 0; c < NCHAIN; ++c) {
        long long row = base_row + (long long)c * 256;
        rowid[c] = row;
        x[c] = 0;
        if (row < n_rows) {
            long long base = row * 3;
            long long a, b, cc;
            if (nb64) {
                const long long* nb = (const long long*)nbv;
                a = nb[base]; b = nb[base + 1]; cc = nb[base + 2];
            } else {
                const int* nb = (const int*)nbv;
                a = nb[base]; b = nb[base + 1]; cc = nb[base + 2];
            }
            x[c] = 131071LL * a + 524287LL * b + 2147483647LL * cc;
            alive |= 1u << c;
        }
    }

    for (int r = 0; r < rounds; ++r) {
        if (__ballot(alive != 0u) == 0ull) break;

        long long idx[NCHAIN];
        #pragma unroll
        for (int c = 0; c < NCHAIN; ++c) {
            x[c] = hash_step(x[c]);
            idx[c] = ((alive >> c) & 1u) ? mod_d(x[c], d, M) : 0ll;
        }
        // 4 independent gathers issued back-to-back (dead chains: line 0)
        bool bit[NCHAIN];
        #pragma unroll
        for (int c = 0; c < NCHAIN; ++c)
            bit[c] = probe(bitsv, bdt, idx[c]);
        #pragma unroll
        for (int c = 0; c < NCHAIN; ++c)
            if (!bit[c]) alive &= ~(1u << c);
    }

    #pragma unroll
    for (int c = 0; c < NCHAIN; ++c)
        if (rowid[c] < n_rows)
            out[rowid[c]] = ((alive >> c) & 1u) ? 0 : 1;
}

extern "C" void kernel_launch(void* const* d_in, const int* in_sizes, int n_in,
                              void* d_out, int out_size, void* d_ws, size_t ws_size,
                              hipStream_t stream)
{
    const void* nb       = d_in[0];
    const void* bits     = d_in[1];
    // d_in[2] = mersenne (1,3) — constants hardcoded
    const uint32_t* rnds = (const uint32_t*)d_in[3];

    int n_rows  = in_sizes[0] / 3;
    long long d = (long long)in_sizes[1];

    unsigned long long M =
        (unsigned long long)(((unsigned __int128)1 << 89) / (unsigned long long)d);

    int rows_per_block = 256 * NCHAIN;
    int blocks = (n_rows + rows_per_block - 1) / rows_per_block;
    bloom_mc<<<blocks, 256, 0, stream>>>(nb, bits, rnds, (int*)d_out,
                                         n_rows, d, M);
}

// Round 6
// 56.870 us; speedup vs baseline: 1.9988x; 1.0879x over previous
//
#include <hip/hip_runtime.h>
#include <stdint.h>

// BloomFilterer forward:
//   x = 131071*a + 524287*b + 2147483647*c   (int64)
//   repeat rounds(=10): x = hash(x); result &= bit_array[x mod num_bits]
//   out = (int32) !result
//
// Round 6: NCHAIN=2 -> 8192 waves = full 32 waves/CU (one complete occupancy
// generation). Same minimal probe traffic (~2.1M lines, early-exit); per-CU
// outstanding requests unchanged; finer wave stagger smooths the round-sync
// bursts and hides tail latency.

#define HASH_C1 2146121005ull
#define HASH_C2 2221713035ull
#define NCHAIN 2

__device__ __forceinline__ long long hash_step(long long x) {
    x = x ^ (x >> 16);
    x = (long long)((unsigned long long)x * HASH_C1);
    x = x ^ (x >> 15);
    x = (long long)((unsigned long long)x * HASH_C2);
    x = x ^ (x >> 16);
    return x;
}

// floored mod d (matches jnp.mod), Barrett with M = floor(2^89/d), d in (2^27,2^28)
__device__ __forceinline__ long long mod_d(long long x, long long d,
                                           unsigned long long M) {
    bool neg = x < 0;
    unsigned long long u = neg ? (0ull - (unsigned long long)x)
                               : (unsigned long long)x;
    unsigned long long q  = __umul64hi(u, M) >> 25;
    unsigned long long rr = u - q * (unsigned long long)d;
    if (rr >= (unsigned long long)d) rr -= (unsigned long long)d;
    if (rr >= (unsigned long long)d) rr -= (unsigned long long)d;
    return neg ? (rr ? d - (long long)rr : 0ll) : (long long)rr;
}

__device__ __forceinline__ bool probe(const void* bitsv, int bdt, long long idx) {
    if (bdt == 0)      return ((const uint8_t*)bitsv)[idx] != 0;
    else if (bdt == 1) return ((const uint32_t*)bitsv)[idx] != 0u;
    else               return ((const unsigned long long*)bitsv)[idx] != 0ull;
}

__global__ __launch_bounds__(256, 8) void bloom_mc(
    const void* __restrict__ nbv,
    const void* __restrict__ bitsv,
    const uint32_t* __restrict__ rounds_p,
    int* __restrict__ out,
    int n_rows,
    long long d,
    unsigned long long M)
{
    __shared__ int s_nb64, s_bdt, s_rounds;

    // ---- per-block dtype detection, wave 0, lane-parallel ----
    if (threadIdx.x < 64) {
        int lane = threadIdx.x;
        const uint32_t* bw = (const uint32_t*)bitsv;
        bool anyf = false, alli = true, oddz = true;
        #pragma unroll
        for (int j = 0; j < 8; ++j) {
            int i = lane * 8 + j;
            uint32_t w = bw[i];
            if (w == 0x3F800000u) anyf = true;
            if (w > 1u) alli = false;
            if ((i & 1) && w != 0u) oddz = false;
        }
        unsigned long long m_anyf = __ballot(anyf);
        unsigned long long m_alli = __ballot(alli);
        unsigned long long m_oddz = __ballot(oddz);
        const uint32_t* nw = (const uint32_t*)nbv;
        bool odd_nz = (lane < 16) ? (nw[2 * lane + 1] != 0u) : false;
        unsigned long long m_nb = __ballot(odd_nz);
        if (lane == 0) {
            int bdt;
            if (m_anyf != 0ull)       bdt = 1;                         // float32
            else if (m_alli == ~0ull) bdt = (m_oddz == ~0ull) ? 3 : 1; // int64:int32
            else                      bdt = 0;                         // uint8
            s_bdt    = bdt;
            s_nb64   = (m_nb == 0ull) ? 1 : 0;
            s_rounds = (int)rounds_p[0];
        }
    }
    __syncthreads();

    const int nb64   = s_nb64;
    const int bdt    = s_bdt;
    const int rounds = s_rounds;

    const long long base_row = (long long)blockIdx.x * (256 * NCHAIN) + threadIdx.x;

    long long x[NCHAIN];
    long long rowid[NCHAIN];
    unsigned alive = 0;

    #pragma unroll
    for (int c = 0; c < NCHAIN; ++c) {
        long long row = base_row + (long long)c * 256;
        rowid[c] = row;
        x[c] = 0;
        if (row < n_rows) {
            long long base = row * 3;
            long long a, b, cc;
            if (nb64) {
                const long long* nb = (const long long*)nbv;
                a = nb[base]; b = nb[base + 1]; cc = nb[base + 2];
            } else {
                const int* nb = (const int*)nbv;
                a = nb[base]; b = nb[base + 1]; cc = nb[base + 2];
            }
            x[c] = 131071LL * a + 524287LL * b + 2147483647LL * cc;
            alive |= 1u << c;
        }
    }

    for (int r = 0; r < rounds; ++r) {
        if (__ballot(alive != 0u) == 0ull) break;

        long long idx[NCHAIN];
        #pragma unroll
        for (int c = 0; c < NCHAIN; ++c) {
            x[c] = hash_step(x[c]);
            idx[c] = ((alive >> c) & 1u) ? mod_d(x[c], d, M) : 0ll;
        }
        // independent gathers issued back-to-back (dead chains: line 0)
        bool bit[NCHAIN];
        #pragma unroll
        for (int c = 0; c < NCHAIN; ++c)
            bit[c] = probe(bitsv, bdt, idx[c]);
        #pragma unroll
        for (int c = 0; c < NCHAIN; ++c)
            if (!bit[c]) alive &= ~(1u << c);
    }

    #pragma unroll
    for (int c = 0; c < NCHAIN; ++c)
        if (rowid[c] < n_rows)
            out[rowid[c]] = ((alive >> c) & 1u) ? 0 : 1;
}

extern "C" void kernel_launch(void* const* d_in, const int* in_sizes, int n_in,
                              void* d_out, int out_size, void* d_ws, size_t ws_size,
                              hipStream_t stream)
{
    const void* nb       = d_in[0];
    const void* bits     = d_in[1];
    // d_in[2] = mersenne (1,3) — constants hardcoded
    const uint32_t* rnds = (const uint32_t*)d_in[3];

    int n_rows  = in_sizes[0] / 3;
    long long d = (long long)in_sizes[1];

    unsigned long long M =
        (unsigned long long)(((unsigned __int128)1 << 89) / (unsigned long long)d);

    int rows_per_block = 256 * NCHAIN;
    int blocks = (n_rows + rows_per_block - 1) / rows_per_block;
    bloom_mc<<<blocks, 256, 0, stream>>>(nb, bits, rnds, (int*)d_out,
                                         n_rows, d, M);
}